// Round 1
// baseline (1374.645 us; speedup 1.0000x reference)
//
#include <hip/hip_runtime.h>

// ---------------------------------------------------------------------------
// GraphSAGE 3-layer forward, fp32.
//   cnt/CSR build -> per-layer: aggregate(mean) -> [agg,z]@[Wl;Wr]^T+b -> L2norm -> relu
//   -> final linear to C=40.
// ---------------------------------------------------------------------------

__device__ __forceinline__ float bcast(float v, int l) {
  return __int_as_float(__builtin_amdgcn_readlane(__float_as_int(v), l));
}

// ---------------- CSR build ----------------

__global__ void count_deg_k(const int* __restrict__ dst, int* __restrict__ cnt, int E) {
  int e = blockIdx.x * 256 + threadIdx.x;
  if (e < E) atomicAdd(&cnt[dst[e]], 1);
}

__global__ void scan1_k(const int* __restrict__ cnt, int* __restrict__ bsums, int n) {
  __shared__ int sd[256];
  int base = blockIdx.x * 2048 + threadIdx.x * 8;
  int t = 0;
#pragma unroll
  for (int i = 0; i < 8; i++) { int idx = base + i; if (idx < n) t += cnt[idx]; }
  sd[threadIdx.x] = t; __syncthreads();
  for (int off = 128; off > 0; off >>= 1) {
    if (threadIdx.x < off) sd[threadIdx.x] += sd[threadIdx.x + off];
    __syncthreads();
  }
  if (threadIdx.x == 0) bsums[blockIdx.x] = sd[0];
}

__global__ void scan2_k(int* bsums, int nb) {
  if (blockIdx.x == 0 && threadIdx.x == 0) {
    int run = 0;
    for (int b = 0; b < nb; b++) { int t = bsums[b]; bsums[b] = run; run += t; }
  }
}

__global__ void scan3_k(const int* __restrict__ cnt, const int* __restrict__ bsums,
                        int* __restrict__ offsets, int* __restrict__ cursor,
                        float* __restrict__ inv_cnt, int n, int E) {
  __shared__ int sd[256];
  int base = blockIdx.x * 2048 + threadIdx.x * 8;
  int loc[8]; int t = 0;
#pragma unroll
  for (int i = 0; i < 8; i++) { int idx = base + i; loc[i] = (idx < n) ? cnt[idx] : 0; t += loc[i]; }
  sd[threadIdx.x] = t; __syncthreads();
  for (int off = 1; off < 256; off <<= 1) {
    int u = (threadIdx.x >= (unsigned)off) ? sd[threadIdx.x - off] : 0;
    __syncthreads();
    sd[threadIdx.x] += u;
    __syncthreads();
  }
  int run = bsums[blockIdx.x] + sd[threadIdx.x] - t;  // exclusive prefix for this thread
#pragma unroll
  for (int i = 0; i < 8; i++) {
    int idx = base + i;
    if (idx < n) {
      offsets[idx] = run;
      cursor[idx]  = run;
      int c = loc[i] > 1 ? loc[i] : 1;
      inv_cnt[idx] = 1.0f / (float)c;
      run += loc[i];
    }
  }
  if (blockIdx.x == 0 && threadIdx.x == 0) offsets[n] = E;
}

__global__ void bucket_k(const int* __restrict__ src, const int* __restrict__ dst,
                         int* __restrict__ cursor, int* __restrict__ esrc, int E) {
  int e = blockIdx.x * 256 + threadIdx.x;
  if (e < E) {
    int d = dst[e];
    int pos = atomicAdd(&cursor[d], 1);
    esrc[pos] = src[e];
  }
}

// ---------------- weight pre-transpose ----------------
// WT[m][k*128+j] = W[layer][j*128+k], m = 2*layer + (0:Wl, 1:Wr)
__global__ void transpose_w_k(const float* __restrict__ Wl, const float* __restrict__ Wr,
                              float* __restrict__ WT) {
  int idx = blockIdx.x * 256 + threadIdx.x;          // 0 .. 6*16384
  if (idx >= 6 * 16384) return;
  int m = idx >> 14; int r = idx & 16383;
  int j = r >> 7; int k = r & 127;
  int layer = m >> 1;
  const float* W = (m & 1) ? Wr : Wl;
  WT[m * 16384 + k * 128 + j] = W[layer * 16384 + j * 128 + k];
}

// WlinT[k*40+c] = Wlin[c*128+k]
__global__ void transpose_lin_k(const float* __restrict__ Wlin, float* __restrict__ WlinT) {
  int idx = blockIdx.x * 256 + threadIdx.x;          // 0 .. 5120
  if (idx >= 40 * 128) return;
  int c = idx >> 7; int k = idx & 127;
  WlinT[k * 40 + c] = Wlin[idx];
}

// ---------------- aggregation: one wave per node ----------------
__global__ void aggregate_k(const float* __restrict__ z, const int* __restrict__ offsets,
                            const int* __restrict__ esrc, const float* __restrict__ inv_cnt,
                            float* __restrict__ agg, int n) {
  int gtid = blockIdx.x * 256 + threadIdx.x;
  int w = gtid >> 6;
  int lane = threadIdx.x & 63;
  if (w >= n) return;
  int beg = offsets[w], end = offsets[w + 1];
  float ax = 0.f, ay = 0.f;
  for (int e = beg; e < end; ++e) {
    int s = esrc[e];
    float2 v = ((const float2*)(z + (size_t)s * 128))[lane];
    ax += v.x; ay += v.y;
  }
  float ic = inv_cnt[w];
  float2 o; o.x = ax * ic; o.y = ay * ic;
  ((float2*)(agg + (size_t)w * 128))[lane] = o;
}

// ---------------- SAGE layer: out = agg@WlT + bl + z@WrT, L2-norm, relu ----------------
// out may alias agg (per-node read-before-write within the owning wave).
__global__ __launch_bounds__(512) void sage_layer_k(
    const float* __restrict__ z, const float* agg,
    const float* __restrict__ WlT, const float* __restrict__ WrT,
    const float* __restrict__ bl, float* out, int n) {
  __shared__ float wl[16384];
  __shared__ float wr[16384];
  for (int i = threadIdx.x; i < 4096; i += 512) {
    ((float4*)wl)[i] = ((const float4*)WlT)[i];
    ((float4*)wr)[i] = ((const float4*)WrT)[i];
  }
  __syncthreads();

  int lane = threadIdx.x & 63;
  int gw = (blockIdx.x * 512 + threadIdx.x) >> 6;
  int nw = (gridDim.x * 512) >> 6;
  float b0 = bl[2 * lane], b1 = bl[2 * lane + 1];

  for (int v0 = gw * 8; v0 < n; v0 += nw * 8) {
    float alo[8], ahi[8], zlo[8], zhi[8];
#pragma unroll
    for (int b = 0; b < 8; b++) {
      int v = v0 + b;
      bool ok = v < n;
      size_t off = (size_t)v * 128;
      alo[b] = ok ? agg[off + lane] : 0.f;
      ahi[b] = ok ? agg[off + 64 + lane] : 0.f;
      zlo[b] = ok ? z[off + lane] : 0.f;
      zhi[b] = ok ? z[off + 64 + lane] : 0.f;
    }
    float accA[8], accB[8];
#pragma unroll
    for (int b = 0; b < 8; b++) { accA[b] = 0.f; accB[b] = 0.f; }

#pragma unroll 8
    for (int k = 0; k < 64; k++) {
      float2 wlv = ((const float2*)(wl + k * 128))[lane];
      float2 wrv = ((const float2*)(wr + k * 128))[lane];
#pragma unroll
      for (int b = 0; b < 8; b++) {
        float ak = bcast(alo[b], k);
        float zk = bcast(zlo[b], k);
        accA[b] = fmaf(ak, wlv.x, accA[b]);
        accB[b] = fmaf(ak, wlv.y, accB[b]);
        accA[b] = fmaf(zk, wrv.x, accA[b]);
        accB[b] = fmaf(zk, wrv.y, accB[b]);
      }
    }
#pragma unroll 8
    for (int k = 64; k < 128; k++) {
      float2 wlv = ((const float2*)(wl + k * 128))[lane];
      float2 wrv = ((const float2*)(wr + k * 128))[lane];
#pragma unroll
      for (int b = 0; b < 8; b++) {
        float ak = bcast(ahi[b], k - 64);
        float zk = bcast(zhi[b], k - 64);
        accA[b] = fmaf(ak, wlv.x, accA[b]);
        accB[b] = fmaf(ak, wlv.y, accB[b]);
        accA[b] = fmaf(zk, wrv.x, accA[b]);
        accB[b] = fmaf(zk, wrv.y, accB[b]);
      }
    }

#pragma unroll
    for (int b = 0; b < 8; b++) {
      int v = v0 + b;
      if (v >= n) break;
      float oa = accA[b] + b0;
      float ob = accB[b] + b1;
      float s = oa * oa + ob * ob;
#pragma unroll
      for (int m = 1; m < 64; m <<= 1) s += __shfl_xor(s, m);
      float inv = 1.0f / fmaxf(sqrtf(s), 1e-12f);
      float2 o;
      o.x = fmaxf(oa * inv, 0.f);
      o.y = fmaxf(ob * inv, 0.f);
      ((float2*)(out + (size_t)v * 128))[lane] = o;
    }
  }
}

// ---------------- final linear: [N,128] @ [128,40] + b ----------------
__global__ __launch_bounds__(256) void final_linear_k(
    const float* __restrict__ z, const float* __restrict__ WlinT,
    const float* __restrict__ blin, float* __restrict__ out, int n) {
  __shared__ float wt[128 * 40 + 64];
  __shared__ float bs[40];
  for (int i = threadIdx.x; i < 128 * 40; i += 256) wt[i] = WlinT[i];
  if (threadIdx.x < 40) bs[threadIdx.x] = blin[threadIdx.x];
  __syncthreads();

  int lane = threadIdx.x & 63;
  int c = lane < 40 ? lane : 0;
  int wid = (blockIdx.x * 256 + threadIdx.x) >> 6;
  int nw = (gridDim.x * 256) >> 6;
  for (int v = wid; v < n; v += nw) {
    float zlo = z[(size_t)v * 128 + lane];
    float zhi = z[(size_t)v * 128 + 64 + lane];
    float acc = bs[c];
#pragma unroll 8
    for (int k = 0; k < 64; k++) {
      acc = fmaf(bcast(zlo, k), wt[k * 40 + c], acc);
      acc = fmaf(bcast(zhi, k), wt[(k + 64) * 40 + c], acc);
    }
    if (lane < 40) out[(size_t)v * 40 + lane] = acc;
  }
}

// ---------------- launch ----------------

extern "C" void kernel_launch(void* const* d_in, const int* in_sizes, int n_in,
                              void* d_out, int out_size, void* d_ws, size_t ws_size,
                              hipStream_t stream) {
  const float* x    = (const float*)d_in[0];
  const int*   ei   = (const int*)d_in[1];
  const float* Wl   = (const float*)d_in[2];
  const float* bl   = (const float*)d_in[3];
  const float* Wr   = (const float*)d_in[4];
  const float* Wlin = (const float*)d_in[5];
  const float* blin = (const float*)d_in[6];

  const int N = in_sizes[0] / 128;
  const int E = in_sizes[1] / 2;
  const int D = 128;

  const int* src = ei;
  const int* dstp = ei + E;

  // workspace layout (all 4B types)
  float* bufA    = (float*)d_ws;                 // N*128
  float* bufB    = bufA + (size_t)N * D;         // N*128
  float* inv_cnt = bufB + (size_t)N * D;         // N
  float* WT      = inv_cnt + N;                  // 6*16384
  float* WlinT   = WT + 6 * 16384;               // 5120
  int*   offsets = (int*)(WlinT + 5120);         // N+1
  int*   cursor  = offsets + N + 1;              // N
  int*   esrc    = cursor + N;                   // E
  int*   bsums   = esrc + E;                     // <=64

  const int nb = (N + 2047) / 2048;

  // CSR build
  hipMemsetAsync(cursor, 0, (size_t)N * 4, stream);
  count_deg_k<<<(E + 255) / 256, 256, 0, stream>>>(dstp, cursor, E);
  scan1_k<<<nb, 256, 0, stream>>>(cursor, bsums, N);
  scan2_k<<<1, 64, 0, stream>>>(bsums, nb);
  scan3_k<<<nb, 256, 0, stream>>>(cursor, bsums, offsets, cursor, inv_cnt, N, E);
  bucket_k<<<(E + 255) / 256, 256, 0, stream>>>(src, dstp, cursor, esrc, E);

  // weight transposes
  transpose_w_k<<<(6 * 16384 + 255) / 256, 256, 0, stream>>>(Wl, Wr, WT);
  transpose_lin_k<<<(40 * 128 + 255) / 256, 256, 0, stream>>>(Wlin, WlinT);

  const int aggGrid = (int)(((size_t)N * 64 + 255) / 256);

  // layer 1: z = x, agg -> bufA, out -> bufA
  aggregate_k<<<aggGrid, 256, 0, stream>>>(x, offsets, esrc, inv_cnt, bufA, N);
  sage_layer_k<<<256, 512, 0, stream>>>(x, bufA, WT + 0 * 16384, WT + 1 * 16384, bl + 0 * D, bufA, N);
  // layer 2: z = bufA, agg -> bufB, out -> bufB
  aggregate_k<<<aggGrid, 256, 0, stream>>>(bufA, offsets, esrc, inv_cnt, bufB, N);
  sage_layer_k<<<256, 512, 0, stream>>>(bufA, bufB, WT + 2 * 16384, WT + 3 * 16384, bl + 1 * D, bufB, N);
  // layer 3: z = bufB, agg -> bufA, out -> bufA
  aggregate_k<<<aggGrid, 256, 0, stream>>>(bufB, offsets, esrc, inv_cnt, bufA, N);
  sage_layer_k<<<256, 512, 0, stream>>>(bufB, bufA, WT + 4 * 16384, WT + 5 * 16384, bl + 2 * D, bufA, N);

  // final linear
  final_linear_k<<<2048, 256, 0, stream>>>(bufA, WlinT, blin, (float*)d_out, N);
}

// Round 2
// 903.558 us; speedup vs baseline: 1.5214x; 1.5214x over previous
//
#include <hip/hip_runtime.h>

// ---------------------------------------------------------------------------
// GraphSAGE 3-layer forward.
//   CSR build -> per-layer: aggregate(mean) -> MFMA GEMM [agg|z]@[Wl;Wr]^T
//   (bf16 hi/lo split, fp32-accurate) + bias -> L2norm -> relu -> final linear.
// ---------------------------------------------------------------------------

typedef __bf16 bf16x8 __attribute__((ext_vector_type(8)));
typedef float  f32x4  __attribute__((ext_vector_type(4)));

#define MFMA16(a, b, c) __builtin_amdgcn_mfma_f32_16x16x32_bf16((a), (b), (c), 0, 0, 0)

__device__ __forceinline__ unsigned short rne_bf16(float f) {
  unsigned u = __float_as_uint(f);
  unsigned r = u + 0x7FFFu + ((u >> 16) & 1u);
  return (unsigned short)(r >> 16);
}

__device__ __forceinline__ void split_bf16(float f, unsigned short& h, unsigned short& l) {
  h = rne_bf16(f);
  float hf = __uint_as_float(((unsigned)h) << 16);
  l = rne_bf16(f - hf);
}

// ---------------- CSR build ----------------

__global__ void count_deg_k(const int* __restrict__ dst, int* __restrict__ cnt, int E) {
  int e = blockIdx.x * 256 + threadIdx.x;
  if (e < E) atomicAdd(&cnt[dst[e]], 1);
}

__global__ void scan1_k(const int* __restrict__ cnt, int* __restrict__ bsums, int n) {
  __shared__ int sd[256];
  int base = blockIdx.x * 2048 + threadIdx.x * 8;
  int t = 0;
#pragma unroll
  for (int i = 0; i < 8; i++) { int idx = base + i; if (idx < n) t += cnt[idx]; }
  sd[threadIdx.x] = t; __syncthreads();
  for (int off = 128; off > 0; off >>= 1) {
    if (threadIdx.x < off) sd[threadIdx.x] += sd[threadIdx.x + off];
    __syncthreads();
  }
  if (threadIdx.x == 0) bsums[blockIdx.x] = sd[0];
}

__global__ void scan2_k(int* bsums, int nb) {
  if (blockIdx.x == 0 && threadIdx.x == 0) {
    int run = 0;
    for (int b = 0; b < nb; b++) { int t = bsums[b]; bsums[b] = run; run += t; }
  }
}

__global__ void scan3_k(const int* __restrict__ cnt, const int* __restrict__ bsums,
                        int* __restrict__ offsets, int* __restrict__ cursor,
                        float* __restrict__ inv_cnt, int n, int E) {
  __shared__ int sd[256];
  int base = blockIdx.x * 2048 + threadIdx.x * 8;
  int loc[8]; int t = 0;
#pragma unroll
  for (int i = 0; i < 8; i++) { int idx = base + i; loc[i] = (idx < n) ? cnt[idx] : 0; t += loc[i]; }
  sd[threadIdx.x] = t; __syncthreads();
  for (int off = 1; off < 256; off <<= 1) {
    int u = (threadIdx.x >= (unsigned)off) ? sd[threadIdx.x - off] : 0;
    __syncthreads();
    sd[threadIdx.x] += u;
    __syncthreads();
  }
  int run = bsums[blockIdx.x] + sd[threadIdx.x] - t;
#pragma unroll
  for (int i = 0; i < 8; i++) {
    int idx = base + i;
    if (idx < n) {
      offsets[idx] = run;
      cursor[idx]  = run;
      int c = loc[i] > 1 ? loc[i] : 1;
      inv_cnt[idx] = 1.0f / (float)c;
      run += loc[i];
    }
  }
  if (blockIdx.x == 0 && threadIdx.x == 0) offsets[n] = E;
}

__global__ void bucket_k(const int* __restrict__ src, const int* __restrict__ dst,
                         int* __restrict__ cursor, int* __restrict__ esrc, int E) {
  int e = blockIdx.x * 256 + threadIdx.x;
  if (e < E) {
    int d = dst[e];
    int pos = atomicAdd(&cursor[d], 1);
    esrc[pos] = src[e];
  }
}

// ---------------- weight fragment prep (hi/lo bf16, MFMA B-layout) ----------
// Combined weight W'[k][j]: k<128 -> Wl[j][k], k>=128 -> Wr[j][k-128].
// Layout per layer: [part p(0=hi,1=lo)][tile t(8)][chunk c(8)][lane(64)][j(8)]
// lane l holds B[k = c*32 + (l>>4)*8 + j][col = t*16 + (l&15)].
__global__ void wfrag_prep_k(const float* __restrict__ Wl, const float* __restrict__ Wr,
                             unsigned short* __restrict__ wfrag) {
  int id = blockIdx.x * 256 + threadIdx.x;
  if (id >= 3 * 2 * 8 * 8 * 64) return;
  int l = id & 63;
  int c = (id >> 6) & 7;
  int t = (id >> 9) & 7;
  int p = (id >> 12) & 1;
  int layer = id >> 13;
  int col = t * 16 + (l & 15);
  int kbase = c * 32 + (l >> 4) * 8;
  unsigned short* dst = wfrag + (size_t)layer * 65536 +
                        ((((size_t)p * 8 + t) * 8 + c) * 64 + l) * 8;
#pragma unroll
  for (int j = 0; j < 8; ++j) {
    int k = kbase + j;
    float w = (k < 128) ? Wl[layer * 16384 + col * 128 + k]
                        : Wr[layer * 16384 + col * 128 + (k - 128)];
    unsigned short h = rne_bf16(w);
    unsigned short o;
    if (p == 0) o = h;
    else {
      float hf = __uint_as_float(((unsigned)h) << 16);
      o = rne_bf16(w - hf);
    }
    dst[j] = o;
  }
}

// WlinT[k*40+c] = Wlin[c*128+k]
__global__ void transpose_lin_k(const float* __restrict__ Wlin, float* __restrict__ WlinT) {
  int idx = blockIdx.x * 256 + threadIdx.x;
  if (idx >= 40 * 128) return;
  int c = idx >> 7; int k = idx & 127;
  WlinT[k * 40 + c] = Wlin[idx];
}

// ---------------- aggregation: one wave per node ----------------
__global__ void aggregate_k(const float* __restrict__ z, const int* __restrict__ offsets,
                            const int* __restrict__ esrc, const float* __restrict__ inv_cnt,
                            float* __restrict__ agg, int n) {
  int gtid = blockIdx.x * 256 + threadIdx.x;
  int w = gtid >> 6;
  int lane = threadIdx.x & 63;
  if (w >= n) return;
  int beg = offsets[w], end = offsets[w + 1];
  float ax = 0.f, ay = 0.f;
  for (int e = beg; e < end; ++e) {
    int s = esrc[e];
    float2 v = ((const float2*)(z + (size_t)s * 128))[lane];
    ax += v.x; ay += v.y;
  }
  float ic = inv_cnt[w];
  float2 o; o.x = ax * ic; o.y = ay * ic;
  ((float2*)(agg + (size_t)w * 128))[lane] = o;
}

// ---------------- SAGE layer via MFMA ----------------
// out = relu(l2norm([agg|z] @ [Wl;Wr]^T + bl)); out may alias agg (row-owned).
// Block: 256 threads = 4 waves; 32 nodes/tile; wave w owns output cols
// [w*32, w*32+32) as two 16-col MFMA tiles. K=256, hi/lo split -> 6 MFMA/chunk.
__global__ __launch_bounds__(256, 2) void sage_layer_mfma_k(
    const float* __restrict__ z, const float* agg,
    const unsigned short* __restrict__ wf, const float* __restrict__ bl,
    float* out, int n, int ntiles) {
  __shared__ unsigned short Ah_s[32 * 256];
  __shared__ unsigned short Al_s[32 * 256];
  __shared__ float psum[2][4][16];

  const int lane = threadIdx.x & 63;
  const int wv = threadIdx.x >> 6;        // 0..3
  const int g = lane >> 4;                // 0..3 (k-group / output row group)
  const int rl = lane & 15;               // row (A) / col (B,D) within tile

  // B fragments: hi+lo for this wave's 2 col-tiles. 128 VGPRs.
  const bf16x8* wfv = (const bf16x8*)wf;  // granularity: 8 ushorts = 16B
  const int t0 = wv * 2, t1 = wv * 2 + 1;
  bf16x8 Bh0[8], Bh1[8], Bl0[8], Bl1[8];
#pragma unroll
  for (int c = 0; c < 8; ++c) {
    Bh0[c] = wfv[((0 * 8 + t0) * 8 + c) * 64 + lane];
    Bh1[c] = wfv[((0 * 8 + t1) * 8 + c) * 64 + lane];
    Bl0[c] = wfv[((1 * 8 + t0) * 8 + c) * 64 + lane];
    Bl1[c] = wfv[((1 * 8 + t1) * 8 + c) * 64 + lane];
  }
  const float b0 = bl[t0 * 16 + rl];
  const float b1 = bl[t1 * 16 + rl];

  char* pAh = (char*)Ah_s;
  char* pAl = (char*)Al_s;

  for (int tile = blockIdx.x; tile < ntiles; tile += gridDim.x) {
    const int v0 = tile * 32;

    // ---- stage A = [agg(128) | z(128)] rows v0..v0+31 as swizzled hi/lo bf16
#pragma unroll
    for (int q = 0; q < 8; ++q) {
      int lin = q * 1024 + threadIdx.x * 4;   // element in [32][256]
      int r = lin >> 8;
      int col = lin & 255;
      int v = v0 + r; v = (v < n) ? v : (n - 1);
      const float* sp = (col < 128) ? (agg + (size_t)v * 128 + col)
                                    : (z + (size_t)v * 128 + (col - 128));
      float4 f = *(const float4*)sp;
      unsigned short h0, l0, h1, l1, h2, l2, h3, l3;
      split_bf16(f.x, h0, l0); split_bf16(f.y, h1, l1);
      split_bf16(f.z, h2, l2); split_bf16(f.w, h3, l3);
      int byte = (r * 512 + col * 2) ^ ((r & 7) << 4);
      *(uint2*)(pAh + byte) = make_uint2(h0 | ((unsigned)h1 << 16), h2 | ((unsigned)h3 << 16));
      *(uint2*)(pAl + byte) = make_uint2(l0 | ((unsigned)l1 << 16), l2 | ((unsigned)l3 << 16));
    }
    __syncthreads();

#pragma unroll
    for (int s = 0; s < 2; ++s) {           // 2 node-subtiles of 16 rows
      f32x4 a0 = {0.f, 0.f, 0.f, 0.f};
      f32x4 a1 = {0.f, 0.f, 0.f, 0.f};
      const int abase = (s * 16 + rl) * 512 + g * 16;
      const int swz = (rl & 7) << 4;
#pragma unroll
      for (int c = 0; c < 8; ++c) {
        int off = (abase + c * 64) ^ swz;
        bf16x8 ah = *(const bf16x8*)(pAh + off);
        bf16x8 al = *(const bf16x8*)(pAl + off);
        a0 = MFMA16(ah, Bh0[c], a0); a1 = MFMA16(ah, Bh1[c], a1);
        a0 = MFMA16(ah, Bl0[c], a0); a1 = MFMA16(ah, Bl1[c], a1);
        a0 = MFMA16(al, Bh0[c], a0); a1 = MFMA16(al, Bh1[c], a1);
      }
      // bias + partial row sum-of-squares
      float pr[4];
#pragma unroll
      for (int j = 0; j < 4; ++j) {
        a0[j] += b0; a1[j] += b1;
        pr[j] = a0[j] * a0[j] + a1[j] * a1[j];
      }
#pragma unroll
      for (int m = 1; m < 16; m <<= 1) {
#pragma unroll
        for (int j = 0; j < 4; ++j) pr[j] += __shfl_xor(pr[j], m);
      }
      if (rl == 0) {
#pragma unroll
        for (int j = 0; j < 4; ++j) psum[s][wv][g * 4 + j] = pr[j];
      }
      __syncthreads();
      // finalize: full-row norms, scale, relu, store
#pragma unroll
      for (int j = 0; j < 4; ++j) {
        int row16 = g * 4 + j;
        float tot = psum[s][0][row16] + psum[s][1][row16] +
                    psum[s][2][row16] + psum[s][3][row16];
        float inv = 1.0f / fmaxf(sqrtf(tot), 1e-12f);
        int v = v0 + s * 16 + row16;
        if (v < n) {
          out[(size_t)v * 128 + t0 * 16 + rl] = fmaxf(a0[j] * inv, 0.f);
          out[(size_t)v * 128 + t1 * 16 + rl] = fmaxf(a1[j] * inv, 0.f);
        }
      }
    }
  }
}

// ---------------- final linear: [N,128] @ [128,40] + b ----------------
__global__ __launch_bounds__(256) void final_linear_k(
    const float* __restrict__ z, const float* __restrict__ WlinT,
    const float* __restrict__ blin, float* __restrict__ out, int n) {
  __shared__ float wt[128 * 40 + 64];
  __shared__ float bs[40];
  for (int i = threadIdx.x; i < 128 * 40; i += 256) wt[i] = WlinT[i];
  if (threadIdx.x < 40) bs[threadIdx.x] = blin[threadIdx.x];
  __syncthreads();

  int lane = threadIdx.x & 63;
  int c = lane < 40 ? lane : 0;
  int wid = (blockIdx.x * 256 + threadIdx.x) >> 6;
  int nw = (gridDim.x * 256) >> 6;
  for (int v = wid; v < n; v += nw) {
    float zlo = z[(size_t)v * 128 + lane];
    float zhi = z[(size_t)v * 128 + 64 + lane];
    float acc = bs[c];
#pragma unroll 8
    for (int k = 0; k < 64; k++) {
      acc = fmaf(__int_as_float(__builtin_amdgcn_readlane(__float_as_int(zlo), k)), wt[k * 40 + c], acc);
      acc = fmaf(__int_as_float(__builtin_amdgcn_readlane(__float_as_int(zhi), k)), wt[(k + 64) * 40 + c], acc);
    }
    if (lane < 40) out[(size_t)v * 40 + lane] = acc;
  }
}

// ---------------- launch ----------------

extern "C" void kernel_launch(void* const* d_in, const int* in_sizes, int n_in,
                              void* d_out, int out_size, void* d_ws, size_t ws_size,
                              hipStream_t stream) {
  const float* x    = (const float*)d_in[0];
  const int*   ei   = (const int*)d_in[1];
  const float* Wl   = (const float*)d_in[2];
  const float* bl   = (const float*)d_in[3];
  const float* Wr   = (const float*)d_in[4];
  const float* Wlin = (const float*)d_in[5];
  const float* blin = (const float*)d_in[6];

  const int N = in_sizes[0] / 128;
  const int E = in_sizes[1] / 2;
  const int D = 128;

  const int* src = ei;
  const int* dstp = ei + E;

  // workspace layout
  float* bufA    = (float*)d_ws;                       // N*128
  float* bufB    = bufA + (size_t)N * D;               // N*128
  float* inv_cnt = bufB + (size_t)N * D;               // N
  float* WlinT   = inv_cnt + N;                        // 5120
  unsigned short* Wfrag = (unsigned short*)(WlinT + 5120);  // 3*65536 ushorts
  int*   offsets = (int*)(Wfrag + 3 * 65536);          // N+1
  int*   cursor  = offsets + N + 1;                    // N
  int*   esrc    = cursor + N;                         // E
  int*   bsums   = esrc + E;                           // <=64

  const int nb = (N + 2047) / 2048;

  // CSR build
  hipMemsetAsync(cursor, 0, (size_t)N * 4, stream);
  count_deg_k<<<(E + 255) / 256, 256, 0, stream>>>(dstp, cursor, E);
  scan1_k<<<nb, 256, 0, stream>>>(cursor, bsums, N);
  scan2_k<<<1, 64, 0, stream>>>(bsums, nb);
  scan3_k<<<nb, 256, 0, stream>>>(cursor, bsums, offsets, cursor, inv_cnt, N, E);
  bucket_k<<<(E + 255) / 256, 256, 0, stream>>>(src, dstp, cursor, esrc, E);

  // weight prep
  wfrag_prep_k<<<96, 256, 0, stream>>>(Wl, Wr, Wfrag);
  transpose_lin_k<<<(40 * 128 + 255) / 256, 256, 0, stream>>>(Wlin, WlinT);

  const int aggGrid = (int)(((size_t)N * 64 + 255) / 256);
  const int ntiles = (N + 31) / 32;
  const int sageGrid = 512;

  // layer 1: z = x, agg -> bufA, out -> bufA
  aggregate_k<<<aggGrid, 256, 0, stream>>>(x, offsets, esrc, inv_cnt, bufA, N);
  sage_layer_mfma_k<<<sageGrid, 256, 0, stream>>>(x, bufA, Wfrag + 0 * 65536, bl + 0 * D, bufA, N, ntiles);
  // layer 2: z = bufA, agg -> bufB, out -> bufB
  aggregate_k<<<aggGrid, 256, 0, stream>>>(bufA, offsets, esrc, inv_cnt, bufB, N);
  sage_layer_mfma_k<<<sageGrid, 256, 0, stream>>>(bufA, bufB, Wfrag + 1 * 65536, bl + 1 * D, bufB, N, ntiles);
  // layer 3: z = bufB, agg -> bufA, out -> bufA
  aggregate_k<<<aggGrid, 256, 0, stream>>>(bufB, offsets, esrc, inv_cnt, bufA, N);
  sage_layer_mfma_k<<<sageGrid, 256, 0, stream>>>(bufB, bufA, Wfrag + 2 * 65536, bl + 2 * D, bufA, N, ntiles);

  // final linear
  final_linear_k<<<2048, 256, 0, stream>>>(bufA, WlinT, blin, (float*)d_out, N);
}

// Round 3
// 633.358 us; speedup vs baseline: 2.1704x; 1.4266x over previous
//
#include <hip/hip_runtime.h>

// ---------------------------------------------------------------------------
// GraphSAGE 3-layer forward.
//   CSR build -> bf16 gather planes -> per-layer: aggregate(mean, bf16 rows)
//   -> MFMA GEMM [agg(hi/lo)|z(bf16)]@[Wl;Wr]^T + bias -> L2norm -> relu
//   -> final linear (bf16 z).
// ---------------------------------------------------------------------------

typedef __bf16 bf16x8 __attribute__((ext_vector_type(8)));
typedef float  f32x4  __attribute__((ext_vector_type(4)));

#define MFMA16(a, b, c) __builtin_amdgcn_mfma_f32_16x16x32_bf16((a), (b), (c), 0, 0, 0)

__device__ __forceinline__ unsigned rne_bf16(float f) {
  unsigned u = __float_as_uint(f);
  unsigned r = u + 0x7FFFu + ((u >> 16) & 1u);
  return r >> 16;
}

__device__ __forceinline__ float bf_lo(unsigned u) { return __uint_as_float(u << 16); }
__device__ __forceinline__ float bf_hi(unsigned u) { return __uint_as_float(u & 0xFFFF0000u); }

// ---------------- CSR build ----------------

__global__ void count_deg_k(const int* __restrict__ dst, int* __restrict__ cnt, int E) {
  int e = blockIdx.x * 256 + threadIdx.x;
  if (e < E) atomicAdd(&cnt[dst[e]], 1);
}

__global__ void scan1_k(const int* __restrict__ cnt, int* __restrict__ bsums, int n) {
  __shared__ int sd[256];
  int base = blockIdx.x * 2048 + threadIdx.x * 8;
  int t = 0;
#pragma unroll
  for (int i = 0; i < 8; i++) { int idx = base + i; if (idx < n) t += cnt[idx]; }
  sd[threadIdx.x] = t; __syncthreads();
  for (int off = 128; off > 0; off >>= 1) {
    if (threadIdx.x < off) sd[threadIdx.x] += sd[threadIdx.x + off];
    __syncthreads();
  }
  if (threadIdx.x == 0) bsums[blockIdx.x] = sd[0];
}

__global__ void scan2_k(int* bsums, int nb) {
  if (blockIdx.x == 0 && threadIdx.x == 0) {
    int run = 0;
    for (int b = 0; b < nb; b++) { int t = bsums[b]; bsums[b] = run; run += t; }
  }
}

__global__ void scan3_k(const int* __restrict__ cnt, const int* __restrict__ bsums,
                        int* __restrict__ offsets, int* __restrict__ cursor,
                        float* __restrict__ inv_cnt, int n, int E) {
  __shared__ int sd[256];
  int base = blockIdx.x * 2048 + threadIdx.x * 8;
  int loc[8]; int t = 0;
#pragma unroll
  for (int i = 0; i < 8; i++) { int idx = base + i; loc[i] = (idx < n) ? cnt[idx] : 0; t += loc[i]; }
  sd[threadIdx.x] = t; __syncthreads();
  for (int off = 1; off < 256; off <<= 1) {
    int u = (threadIdx.x >= (unsigned)off) ? sd[threadIdx.x - off] : 0;
    __syncthreads();
    sd[threadIdx.x] += u;
    __syncthreads();
  }
  int run = bsums[blockIdx.x] + sd[threadIdx.x] - t;
#pragma unroll
  for (int i = 0; i < 8; i++) {
    int idx = base + i;
    if (idx < n) {
      offsets[idx] = run;
      cursor[idx]  = run;
      int c = loc[i] > 1 ? loc[i] : 1;
      inv_cnt[idx] = 1.0f / (float)c;
      run += loc[i];
    }
  }
  if (blockIdx.x == 0 && threadIdx.x == 0) offsets[n] = E;
}

__global__ void bucket_k(const int* __restrict__ src, const int* __restrict__ dst,
                         int* __restrict__ cursor, int* __restrict__ esrc, int E) {
  int e = blockIdx.x * 256 + threadIdx.x;
  if (e < E) {
    int d = dst[e];
    int pos = atomicAdd(&cursor[d], 1);
    esrc[pos] = src[e];
  }
}

// ---------------- fp32 -> bf16 plane ----------------
__global__ void to_bf16_k(const float4* __restrict__ in, uint2* __restrict__ out, int n4) {
  int i = blockIdx.x * 256 + threadIdx.x;
  if (i >= n4) return;
  float4 f = in[i];
  uint2 o;
  o.x = rne_bf16(f.x) | (rne_bf16(f.y) << 16);
  o.y = rne_bf16(f.z) | (rne_bf16(f.w) << 16);
  out[i] = o;
}

// ---------------- weight fragment prep (hi/lo bf16, MFMA B-layout) ----------
// Combined weight W'[k][j]: k<128 -> Wl[j][k], k>=128 -> Wr[j][k-128].
// Layout per layer: [part p(0=hi,1=lo)][tile t(8)][chunk c(8)][lane(64)][j(8)]
// lane l holds B[k = c*32 + (l>>4)*8 + j][col = t*16 + (l&15)].
__global__ void wfrag_prep_k(const float* __restrict__ Wl, const float* __restrict__ Wr,
                             unsigned short* __restrict__ wfrag) {
  int id = blockIdx.x * 256 + threadIdx.x;
  if (id >= 3 * 2 * 8 * 8 * 64) return;
  int l = id & 63;
  int c = (id >> 6) & 7;
  int t = (id >> 9) & 7;
  int p = (id >> 12) & 1;
  int layer = id >> 13;
  int col = t * 16 + (l & 15);
  int kbase = c * 32 + (l >> 4) * 8;
  unsigned short* dst = wfrag + (size_t)layer * 65536 +
                        ((((size_t)p * 8 + t) * 8 + c) * 64 + l) * 8;
#pragma unroll
  for (int j = 0; j < 8; ++j) {
    int k = kbase + j;
    float w = (k < 128) ? Wl[layer * 16384 + col * 128 + k]
                        : Wr[layer * 16384 + col * 128 + (k - 128)];
    unsigned h = rne_bf16(w);
    unsigned o;
    if (p == 0) o = h;
    else o = rne_bf16(w - __uint_as_float(h << 16));
    dst[j] = (unsigned short)o;
  }
}

// WlinT[k*40+c] = Wlin[c*128+k]
__global__ void transpose_lin_k(const float* __restrict__ Wlin, float* __restrict__ WlinT) {
  int idx = blockIdx.x * 256 + threadIdx.x;
  if (idx >= 40 * 128) return;
  int c = idx >> 7; int k = idx & 127;
  WlinT[k * 40 + c] = Wlin[idx];
}

// ---------------- aggregation: one wave per node, bf16 256B rows ----------------
__global__ void aggregate_k(const unsigned short* __restrict__ zb,
                            const int* __restrict__ offsets,
                            const int* __restrict__ esrc,
                            const float* __restrict__ inv_cnt,
                            float* __restrict__ agg, int n) {
  int w = (blockIdx.x * 256 + threadIdx.x) >> 6;
  int lane = threadIdx.x & 63;
  if (w >= n) return;
  int beg = offsets[w], end = offsets[w + 1];
  float ax = 0.f, ay = 0.f;
  int e = beg;
  for (; e + 3 < end; e += 4) {
    int s0 = esrc[e], s1 = esrc[e + 1], s2 = esrc[e + 2], s3 = esrc[e + 3];
    unsigned u0 = *(const unsigned*)(zb + (size_t)s0 * 128 + lane * 2);
    unsigned u1 = *(const unsigned*)(zb + (size_t)s1 * 128 + lane * 2);
    unsigned u2 = *(const unsigned*)(zb + (size_t)s2 * 128 + lane * 2);
    unsigned u3 = *(const unsigned*)(zb + (size_t)s3 * 128 + lane * 2);
    ax += bf_lo(u0); ay += bf_hi(u0);
    ax += bf_lo(u1); ay += bf_hi(u1);
    ax += bf_lo(u2); ay += bf_hi(u2);
    ax += bf_lo(u3); ay += bf_hi(u3);
  }
  for (; e < end; ++e) {
    unsigned u0 = *(const unsigned*)(zb + (size_t)esrc[e] * 128 + lane * 2);
    ax += bf_lo(u0); ay += bf_hi(u0);
  }
  float ic = inv_cnt[w];
  ((float2*)(agg + (size_t)w * 128))[lane] = make_float2(ax * ic, ay * ic);
}

// ---------------- SAGE layer via MFMA ----------------
// out_bf = bf16(relu(l2norm([agg|zb] @ [Wl;Wr]^T + bl)))
// A: K=256 -> k<128: agg (hi/lo split), k>=128: zb (single bf16, lo=0).
// Block: 256 threads = 4 waves; 32 nodes/tile; wave w owns 2 col-tiles.
__global__ __launch_bounds__(256, 2) void sage_layer_mfma_k(
    const unsigned short* __restrict__ zb, const float* __restrict__ agg,
    const unsigned short* __restrict__ wf, const float* __restrict__ bl,
    unsigned short* __restrict__ out_bf, int n, int ntiles) {
  __shared__ unsigned short Ah_s[32 * 256];   // 16 KB: [32 rows][256 k] swizzled
  __shared__ unsigned short Al_s[32 * 128];   // 8 KB:  [32 rows][128 k] (agg lo)
  __shared__ float psum[2][4][16];

  const int lane = threadIdx.x & 63;
  const int wv = threadIdx.x >> 6;        // 0..3
  const int g = lane >> 4;                // 0..3
  const int rl = lane & 15;

  const bf16x8* wfv = (const bf16x8*)wf;
  const int t0 = wv * 2, t1 = wv * 2 + 1;
  bf16x8 Bh0[8], Bh1[8], Bl0[8], Bl1[8];
#pragma unroll
  for (int c = 0; c < 8; ++c) {
    Bh0[c] = wfv[((0 * 8 + t0) * 8 + c) * 64 + lane];
    Bh1[c] = wfv[((0 * 8 + t1) * 8 + c) * 64 + lane];
    Bl0[c] = wfv[((1 * 8 + t0) * 8 + c) * 64 + lane];
    Bl1[c] = wfv[((1 * 8 + t1) * 8 + c) * 64 + lane];
  }
  const float b0 = bl[t0 * 16 + rl];
  const float b1 = bl[t1 * 16 + rl];

  char* pAh = (char*)Ah_s;
  char* pAl = (char*)Al_s;

  for (int tile = blockIdx.x; tile < ntiles; tile += gridDim.x) {
    const int v0 = tile * 32;

    // ---- stage agg rows (hi/lo split), k in [0,128)
#pragma unroll
    for (int q = 0; q < 4; ++q) {
      int lin = q * 1024 + threadIdx.x * 4;   // element in [32][128]
      int r = lin >> 7;
      int col = lin & 127;
      int v = v0 + r; v = (v < n) ? v : (n - 1);
      float4 f = *(const float4*)(agg + (size_t)v * 128 + col);
      unsigned h0 = rne_bf16(f.x), h1 = rne_bf16(f.y);
      unsigned h2 = rne_bf16(f.z), h3 = rne_bf16(f.w);
      unsigned l0 = rne_bf16(f.x - __uint_as_float(h0 << 16));
      unsigned l1 = rne_bf16(f.y - __uint_as_float(h1 << 16));
      unsigned l2 = rne_bf16(f.z - __uint_as_float(h2 << 16));
      unsigned l3 = rne_bf16(f.w - __uint_as_float(h3 << 16));
      int swz = (r & 7) << 4;
      int byteH = (r * 512 + col * 2) ^ swz;
      int byteL = (r * 256 + col * 2) ^ swz;
      *(uint2*)(pAh + byteH) = make_uint2(h0 | (h1 << 16), h2 | (h3 << 16));
      *(uint2*)(pAl + byteL) = make_uint2(l0 | (l1 << 16), l2 | (l3 << 16));
    }
    // ---- stage z rows (bf16 copy), k in [128,256)
#pragma unroll
    for (int q = 0; q < 2; ++q) {
      int lin = q * 2048 + threadIdx.x * 8;   // ushort element in [32][128]
      int r = lin >> 7;
      int col = lin & 127;
      int v = v0 + r; v = (v < n) ? v : (n - 1);
      uint4 d = *(const uint4*)(zb + (size_t)v * 128 + col);
      int byte = (r * 512 + 256 + col * 2) ^ ((r & 7) << 4);
      *(uint4*)(pAh + byte) = d;
    }
    __syncthreads();

#pragma unroll
    for (int s = 0; s < 2; ++s) {
      f32x4 a0 = {0.f, 0.f, 0.f, 0.f};
      f32x4 a1 = {0.f, 0.f, 0.f, 0.f};
      const int rowH = (s * 16 + rl) * 512;
      const int rowL = (s * 16 + rl) * 256;
      const int swz = (rl & 7) << 4;
#pragma unroll
      for (int c = 0; c < 4; ++c) {           // agg half: hi/lo
        int offH = (rowH + c * 64 + g * 16) ^ swz;
        int offL = (rowL + c * 64 + g * 16) ^ swz;
        bf16x8 ah = *(const bf16x8*)(pAh + offH);
        bf16x8 al = *(const bf16x8*)(pAl + offL);
        a0 = MFMA16(ah, Bh0[c], a0); a1 = MFMA16(ah, Bh1[c], a1);
        a0 = MFMA16(ah, Bl0[c], a0); a1 = MFMA16(ah, Bl1[c], a1);
        a0 = MFMA16(al, Bh0[c], a0); a1 = MFMA16(al, Bh1[c], a1);
      }
#pragma unroll
      for (int c = 4; c < 8; ++c) {           // z half: single bf16
        int offH = (rowH + c * 64 + g * 16) ^ swz;
        bf16x8 ah = *(const bf16x8*)(pAh + offH);
        a0 = MFMA16(ah, Bh0[c], a0); a1 = MFMA16(ah, Bh1[c], a1);
        a0 = MFMA16(ah, Bl0[c], a0); a1 = MFMA16(ah, Bl1[c], a1);
      }
      // bias + partial row sum-of-squares
      float pr[4];
#pragma unroll
      for (int j = 0; j < 4; ++j) {
        a0[j] += b0; a1[j] += b1;
        pr[j] = a0[j] * a0[j] + a1[j] * a1[j];
      }
#pragma unroll
      for (int m = 1; m < 16; m <<= 1) {
#pragma unroll
        for (int j = 0; j < 4; ++j) pr[j] += __shfl_xor(pr[j], m);
      }
      if (rl == 0) {
#pragma unroll
        for (int j = 0; j < 4; ++j) psum[s][wv][g * 4 + j] = pr[j];
      }
      __syncthreads();
#pragma unroll
      for (int j = 0; j < 4; ++j) {
        int row16 = g * 4 + j;
        float tot = psum[s][0][row16] + psum[s][1][row16] +
                    psum[s][2][row16] + psum[s][3][row16];
        float inv = 1.0f / fmaxf(sqrtf(tot), 1e-12f);
        int v = v0 + s * 16 + row16;
        if (v < n) {
          float o0 = fmaxf(a0[j] * inv, 0.f);
          float o1 = fmaxf(a1[j] * inv, 0.f);
          out_bf[(size_t)v * 128 + t0 * 16 + rl] = (unsigned short)rne_bf16(o0);
          out_bf[(size_t)v * 128 + t1 * 16 + rl] = (unsigned short)rne_bf16(o1);
        }
      }
    }
  }
}

// ---------------- final linear: [N,128](bf16) @ [128,40] + b ----------------
__global__ __launch_bounds__(256) void final_linear_k(
    const unsigned short* __restrict__ zb, const float* __restrict__ WlinT,
    const float* __restrict__ blin, float* __restrict__ out, int n) {
  __shared__ float wt[128 * 40 + 64];
  __shared__ float bs[40];
  for (int i = threadIdx.x; i < 128 * 40; i += 256) wt[i] = WlinT[i];
  if (threadIdx.x < 40) bs[threadIdx.x] = blin[threadIdx.x];
  __syncthreads();

  int lane = threadIdx.x & 63;
  int c = lane < 40 ? lane : 0;
  int wid = (blockIdx.x * 256 + threadIdx.x) >> 6;
  int nw = (gridDim.x * 256) >> 6;
  for (int v = wid; v < n; v += nw) {
    unsigned u = *(const unsigned*)(zb + (size_t)v * 128 + lane * 2);
    float acc = bs[c];
#pragma unroll 16
    for (int k = 0; k < 64; k++) {
      unsigned w0 = (unsigned)__builtin_amdgcn_readlane((int)u, k);
      acc = fmaf(bf_lo(w0), wt[(2 * k) * 40 + c], acc);
      acc = fmaf(bf_hi(w0), wt[(2 * k + 1) * 40 + c], acc);
    }
    if (lane < 40) out[(size_t)v * 40 + lane] = acc;
  }
}

// ---------------- launch ----------------

extern "C" void kernel_launch(void* const* d_in, const int* in_sizes, int n_in,
                              void* d_out, int out_size, void* d_ws, size_t ws_size,
                              hipStream_t stream) {
  const float* x    = (const float*)d_in[0];
  const int*   ei   = (const int*)d_in[1];
  const float* Wl   = (const float*)d_in[2];
  const float* bl   = (const float*)d_in[3];
  const float* Wr   = (const float*)d_in[4];
  const float* Wlin = (const float*)d_in[5];
  const float* blin = (const float*)d_in[6];

  const int N = in_sizes[0] / 128;
  const int E = in_sizes[1] / 2;
  const int D = 128;

  const int* src = ei;
  const int* dstp = ei + E;

  // workspace layout
  float* bufA            = (float*)d_ws;                     // N*128 fp32 (agg)
  unsigned short* planeA = (unsigned short*)(bufA + (size_t)N * D);   // N*128 bf16
  unsigned short* planeB = planeA + (size_t)N * D;           // N*128 bf16
  float* inv_cnt = (float*)(planeB + (size_t)N * D);         // N
  float* WlinT   = inv_cnt + N;                              // 5120
  unsigned short* Wfrag = (unsigned short*)(WlinT + 5120);   // 3*65536
  int*   offsets = (int*)(Wfrag + 3 * 65536);                // N+1
  int*   cursor  = offsets + N + 1;                          // N
  int*   esrc    = cursor + N;                               // E
  int*   bsums   = esrc + E;                                 // <=64

  const int nb = (N + 2047) / 2048;

  // CSR build
  hipMemsetAsync(cursor, 0, (size_t)N * 4, stream);
  count_deg_k<<<(E + 255) / 256, 256, 0, stream>>>(dstp, cursor, E);
  scan1_k<<<nb, 256, 0, stream>>>(cursor, bsums, N);
  scan2_k<<<1, 64, 0, stream>>>(bsums, nb);
  scan3_k<<<nb, 256, 0, stream>>>(cursor, bsums, offsets, cursor, inv_cnt, N, E);
  bucket_k<<<(E + 255) / 256, 256, 0, stream>>>(src, dstp, cursor, esrc, E);

  // weight prep + bf16 x plane
  wfrag_prep_k<<<96, 256, 0, stream>>>(Wl, Wr, Wfrag);
  transpose_lin_k<<<(40 * 128 + 255) / 256, 256, 0, stream>>>(Wlin, WlinT);
  to_bf16_k<<<((N * 32) + 255) / 256, 256, 0, stream>>>((const float4*)x, (uint2*)planeA, N * 32);

  const int aggGrid = (int)(((size_t)N * 64 + 255) / 256);
  const int ntiles = (N + 31) / 32;
  const int sageGrid = 512;

  // layer 1
  aggregate_k<<<aggGrid, 256, 0, stream>>>(planeA, offsets, esrc, inv_cnt, bufA, N);
  sage_layer_mfma_k<<<sageGrid, 256, 0, stream>>>(planeA, bufA, Wfrag + 0 * 65536, bl + 0 * D, planeB, N, ntiles);
  // layer 2
  aggregate_k<<<aggGrid, 256, 0, stream>>>(planeB, offsets, esrc, inv_cnt, bufA, N);
  sage_layer_mfma_k<<<sageGrid, 256, 0, stream>>>(planeB, bufA, Wfrag + 1 * 65536, bl + 1 * D, planeA, N, ntiles);
  // layer 3
  aggregate_k<<<aggGrid, 256, 0, stream>>>(planeA, offsets, esrc, inv_cnt, bufA, N);
  sage_layer_mfma_k<<<sageGrid, 256, 0, stream>>>(planeA, bufA, Wfrag + 2 * 65536, bl + 2 * D, planeB, N, ntiles);

  // final linear
  final_linear_k<<<2048, 256, 0, stream>>>(planeB, WlinT, blin, (float*)d_out, N);
}